// Round 3
// baseline (36496.530 us; speedup 1.0000x reference)
//
#include <hip/hip_runtime.h>
#include <hip/hip_bf16.h>
#include <hip/hip_cooperative_groups.h>

namespace cg = cooperative_groups;

#define B_SZ   256
#define T_SZ   256
#define FUT    32
#define TF_SZ  (T_SZ + FUT)
#define HIDN   1024
#define INDIM  64
#define OUTDIM 64

typedef __attribute__((ext_vector_type(8))) short bf16x8;
typedef __attribute__((ext_vector_type(4))) float f32x4;

__device__ __forceinline__ float bf2f(unsigned short u) {
    union { unsigned int i; float f; } v; v.i = (unsigned int)u << 16; return v.f;
}
__device__ __forceinline__ unsigned short f2bf(float f) {
    union { float f; unsigned int i; } v; v.f = f;
    unsigned int r = v.i + 0x7FFFu + ((v.i >> 16) & 1u);
    return (unsigned short)(r >> 16);
}
__device__ __forceinline__ float sigm(float x) { return 1.0f / (1.0f + __expf(-x)); }

// ---------------------------------------------------------------------------
// Persistent 2-layer LSTM. Grid 256 x 512 (1 block/CU, 8 waves).
// Block (bg,bb): owns hidden units j in [bg*8, bg*8+8) (x4 gates = 32 W rows)
// and batch rows [bb*128, bb*128+128).
// Wave ks (0..7) holds register-resident W fragments (A-operand) for a K-slice
// of both layers; B-operand (activations) read straight from global per step.
// K-partials reduced via LDS, cell epilogue in-block. Grid sync between phases.
// ---------------------------------------------------------------------------
__global__ __launch_bounds__(512, 2) void lstm_persist(
    const unsigned short* __restrict__ xbf,    // [256][256][64]
    unsigned short* __restrict__ xfut,         // [256][64]
    const unsigned short* __restrict__ W1,     // [4096][1088]  rows g*1024+j, k=[x|h1]
    const unsigned short* __restrict__ W2,     // [4096][2048]  k=[h1|h2]
    const unsigned short* __restrict__ Wlin,   // [64][1024]
    const unsigned short* __restrict__ Wo2i,   // [64][64]
    const float* __restrict__ b_ih1, const float* __restrict__ b_hh1,
    const float* __restrict__ b_ih2, const float* __restrict__ b_hh2,
    const float* __restrict__ blin, const float* __restrict__ bo2i,
    float* __restrict__ c1, float* __restrict__ c2,
    unsigned short* __restrict__ hh0,          // [256][2048] = [h1|h2], even t src
    unsigned short* __restrict__ hh1,
    float* __restrict__ outp)                  // [256][288][64] f32
{
    __shared__ float part[8][32][130];   // [kslice][gate-row32][batch128+pad]
    __shared__ float red[4][128];        // out-fold partials / fb staging

    cg::grid_group grid = cg::this_grid();

    const int tid  = threadIdx.x;
    const int id   = blockIdx.x;
    const int bg   = id & 127;           // hidden-unit group (8 units)
    const int bb   = id >> 7;            // batch half
    const int ks   = tid >> 6;           // K-slice / wave id
    const int lane = tid & 63;
    const int am   = lane & 15, ah = lane >> 4;

    // W row for fragment row am: frag0 -> gates i/f, frag1 -> gates g/o
    const int wr0 = ((am >> 3)) * 1024 + bg * 8 + (am & 7);
    const int wr1 = (2 + (am >> 3)) * 1024 + bg * 8 + (am & 7);

    // ---- load register-resident W fragments (once) ----
    bf16x8 w2r[2][8];
    {
        const size_t b0 = (size_t)wr0 * 2048 + ks * 256 + ah * 8;
        const size_t b1 = (size_t)wr1 * 2048 + ks * 256 + ah * 8;
#pragma unroll
        for (int kk = 0; kk < 8; ++kk) {
            w2r[0][kk] = *(const bf16x8*)(W2 + b0 + kk * 32);
            w2r[1][kk] = *(const bf16x8*)(W2 + b1 + kk * 32);
        }
    }
    const int kb1 = (ks < 2) ? ks * 160 : 320 + (ks - 2) * 128;   // layer1 K base
    const int kc1 = (ks < 2) ? 5 : 4;                             // k-steps in slice
    bf16x8 w1r[2][5];
#pragma unroll
    for (int gf = 0; gf < 2; ++gf)
#pragma unroll
        for (int kk = 0; kk < 5; ++kk)
            w1r[gf][kk] = (bf16x8){0,0,0,0,0,0,0,0};
    {
        const size_t b0 = (size_t)wr0 * 1088 + kb1 + ah * 8;
        const size_t b1 = (size_t)wr1 * 1088 + kb1 + ah * 8;
#pragma unroll
        for (int kk = 0; kk < 5; ++kk) if (kk < kc1) {
            w1r[0][kk] = *(const bf16x8*)(W1 + b0 + kk * 32);
            w1r[1][kk] = *(const bf16x8*)(W1 + b1 + kk * 32);
        }
    }

    for (int t = 0; t < TF_SZ; ++t) {
        const unsigned short* hsrc = (t & 1) ? hh1 : hh0;  // h(t-1): [h1|h2]
        unsigned short*       hdst = (t & 1) ? hh0 : hh1;  // h(t)

        // ================= phase 1: layer 1 (+ folded out(t-1)) =============
        if (t >= 1 && t <= 255 && bg < 64) {
            // out(t-1)[rows bb*128..+128][col bg] = h2(t-1) . Wlin[bg]
            const int r  = tid & 127, kq = tid >> 7;
            const unsigned short* hrow = hsrc + (size_t)(bb * 128 + r) * 2048 + 1024 + kq * 256;
            const unsigned short* wl   = Wlin + (size_t)bg * 1024 + kq * 256;
            float pp = 0.f;
            for (int k = 0; k < 256; k += 8) {
                bf16x8 hv = *(const bf16x8*)(hrow + k);
                bf16x8 wv = *(const bf16x8*)(wl + k);
#pragma unroll
                for (int u = 0; u < 8; ++u)
                    pp += bf2f((unsigned short)hv[u]) * bf2f((unsigned short)wv[u]);
            }
            red[kq][r] = pp;
            __syncthreads();
            if (tid < 128) {
                float s = red[0][tid] + red[1][tid] + red[2][tid] + red[3][tid] + blin[bg];
                outp[((size_t)(bb * 128 + tid) * TF_SZ + (t - 1)) * OUTDIM + bg] = s;
            }
            __syncthreads();
        }

        const unsigned short* xsrc = (t < T_SZ) ? (xbf + (size_t)t * B_SZ * INDIM) : xfut;

        {
            f32x4 a0[8], a1[8];
#pragma unroll
            for (int nf = 0; nf < 8; ++nf) { a0[nf] = (f32x4){0,0,0,0}; a1[nf] = (f32x4){0,0,0,0}; }
#pragma unroll
            for (int nf = 0; nf < 8; ++nf) {
                const int brow = bb * 128 + nf * 16 + am;
#pragma unroll
                for (int kk = 0; kk < 5; ++kk) if (kk < kc1) {
                    const int k = kb1 + kk * 32 + ah * 8;
                    const unsigned short* bp = (k < 64)
                        ? (xsrc + (size_t)brow * INDIM + k)
                        : (hsrc + (size_t)brow * 2048 + (k - 64));
                    bf16x8 hf = *(const bf16x8*)bp;
                    a0[nf] = __builtin_amdgcn_mfma_f32_16x16x32_bf16(w1r[0][kk], hf, a0[nf], 0, 0, 0);
                    a1[nf] = __builtin_amdgcn_mfma_f32_16x16x32_bf16(w1r[1][kk], hf, a1[nf], 0, 0, 0);
                }
            }
#pragma unroll
            for (int nf = 0; nf < 8; ++nf)
#pragma unroll
                for (int r = 0; r < 4; ++r) {
                    part[ks][ah * 4 + r][nf * 16 + am]      = a0[nf][r];
                    part[ks][16 + ah * 4 + r][nf * 16 + am] = a1[nf][r];
                }
        }
        __syncthreads();
        // layer-1 cell epilogue: 2 cells/thread
#pragma unroll
        for (int ii = 0; ii < 2; ++ii) {
            const int cidx = tid + ii * 512;
            const int jq = cidx >> 7, bl = cidx & 127;
            const int j = bg * 8 + jq;
            const int brow = bb * 128 + bl;
            float g0 = 0.f, g1 = 0.f, g2 = 0.f, g3 = 0.f;
#pragma unroll
            for (int s = 0; s < 8; ++s) {
                g0 += part[s][jq][bl];      g1 += part[s][8 + jq][bl];
                g2 += part[s][16 + jq][bl]; g3 += part[s][24 + jq][bl];
            }
            const float gi = sigm(g0 + b_ih1[j] + b_hh1[j]);
            const float gf = sigm(g1 + b_ih1[HIDN + j] + b_hh1[HIDN + j]);
            const float gg = tanhf(g2 + b_ih1[2 * HIDN + j] + b_hh1[2 * HIDN + j]);
            const float go = sigm(g3 + b_ih1[3 * HIDN + j] + b_hh1[3 * HIDN + j]);
            const size_t ci = (size_t)brow * HIDN + j;
            const float cn = gf * c1[ci] + gi * gg;
            c1[ci] = cn;
            hdst[(size_t)brow * 2048 + j] = f2bf(go * tanhf(cn));
        }
        grid.sync();

        // ================= phase 2: layer 2 =================================
        {
            const unsigned short* hb2 = (ks < 4) ? hdst : hsrc;  // k<1024: h1(t), else h2(t-1)
            f32x4 a0[8], a1[8];
#pragma unroll
            for (int nf = 0; nf < 8; ++nf) { a0[nf] = (f32x4){0,0,0,0}; a1[nf] = (f32x4){0,0,0,0}; }
#pragma unroll
            for (int nf = 0; nf < 8; ++nf) {
                const int brow = bb * 128 + nf * 16 + am;
                const unsigned short* bp = hb2 + (size_t)brow * 2048 + ks * 256 + ah * 8;
#pragma unroll
                for (int kk = 0; kk < 8; ++kk) {
                    bf16x8 hf = *(const bf16x8*)(bp + kk * 32);
                    a0[nf] = __builtin_amdgcn_mfma_f32_16x16x32_bf16(w2r[0][kk], hf, a0[nf], 0, 0, 0);
                    a1[nf] = __builtin_amdgcn_mfma_f32_16x16x32_bf16(w2r[1][kk], hf, a1[nf], 0, 0, 0);
                }
            }
#pragma unroll
            for (int nf = 0; nf < 8; ++nf)
#pragma unroll
                for (int r = 0; r < 4; ++r) {
                    part[ks][ah * 4 + r][nf * 16 + am]      = a0[nf][r];
                    part[ks][16 + ah * 4 + r][nf * 16 + am] = a1[nf][r];
                }
        }
        __syncthreads();
#pragma unroll
        for (int ii = 0; ii < 2; ++ii) {
            const int cidx = tid + ii * 512;
            const int jq = cidx >> 7, bl = cidx & 127;
            const int j = bg * 8 + jq;
            const int brow = bb * 128 + bl;
            float g0 = 0.f, g1 = 0.f, g2 = 0.f, g3 = 0.f;
#pragma unroll
            for (int s = 0; s < 8; ++s) {
                g0 += part[s][jq][bl];      g1 += part[s][8 + jq][bl];
                g2 += part[s][16 + jq][bl]; g3 += part[s][24 + jq][bl];
            }
            const float gi = sigm(g0 + b_ih2[j] + b_hh2[j]);
            const float gf = sigm(g1 + b_ih2[HIDN + j] + b_hh2[HIDN + j]);
            const float gg = tanhf(g2 + b_ih2[2 * HIDN + j] + b_hh2[2 * HIDN + j]);
            const float go = sigm(g3 + b_ih2[3 * HIDN + j] + b_hh2[3 * HIDN + j]);
            const size_t ci = (size_t)brow * HIDN + j;
            const float cn = gf * c2[ci] + gi * gg;
            c2[ci] = cn;
            hdst[(size_t)brow * 2048 + 1024 + j] = f2bf(go * tanhf(cn));
        }
        grid.sync();

        // ================= phase 3 (t>=255): out(t) + feedback ==============
        if (t >= T_SZ - 1) {
            if (id < 32) {
                unsigned short* h2s = (unsigned short*)&part[0][0][0];  // [8][1024]
                const int rowbase = id * 8;
                for (int i = tid; i < 1024; i += 512) {
                    const int rr = i >> 7, k8 = (i & 127) * 8;
                    *(bf16x8*)&h2s[rr * 1024 + k8] =
                        *(const bf16x8*)&hdst[(size_t)(rowbase + rr) * 2048 + 1024 + k8];
                }
                __syncthreads();
                const int rl = tid >> 6, col = tid & 63;
                float acc = blin[col];
                const unsigned short* wl = Wlin + (size_t)col * HIDN;
                for (int k = 0; k < HIDN; k += 8) {
                    bf16x8 hv = *(const bf16x8*)&h2s[rl * 1024 + k];
                    bf16x8 wv = *(const bf16x8*)&wl[k];
#pragma unroll
                    for (int u = 0; u < 8; ++u)
                        acc += bf2f((unsigned short)hv[u]) * bf2f((unsigned short)wv[u]);
                }
                outp[((size_t)(rowbase + rl) * TF_SZ + t) * OUTDIM + col] = acc;
                if (t < TF_SZ - 1) {
                    float* outs = &red[0][0];                // [8][64]
                    outs[rl * 64 + col] = acc;
                    __syncthreads();
                    float x = bo2i[col];
                    const unsigned short* w2 = Wo2i + (size_t)col * OUTDIM;
#pragma unroll 8
                    for (int jj = 0; jj < OUTDIM; ++jj)
                        x += outs[rl * 64 + jj] * bf2f(w2[jj]);
                    xfut[(size_t)(rowbase + rl) * INDIM + col] = f2bf(x);
                }
            }
            grid.sync();
        }
    }
}

// fp32 -> bf16 with strided destination (row interleave for [W_ih | W_hh])
__global__ void conv_strided(const float* __restrict__ src,
                             unsigned short* __restrict__ dst,
                             int cols, int dstride, int doff, int total)
{
    const int idx = blockIdx.x * 256 + threadIdx.x;
    if (idx >= total) return;
    const int r = idx / cols, c = idx - r * cols;
    dst[(size_t)r * dstride + doff + c] = f2bf(src[idx]);
}

// input [B][T][F] fp32 -> [T][B][F] bf16
__global__ void conv_x(const float* __restrict__ src,
                       unsigned short* __restrict__ dst)
{
    const int idx = blockIdx.x * 256 + threadIdx.x;
    const int f = idx & 63, t = (idx >> 6) & 255, b = idx >> 14;
    dst[((size_t)t * B_SZ + b) * INDIM + f] = f2bf(src[idx]);
}

extern "C" void kernel_launch(void* const* d_in, const int* in_sizes, int n_in,
                              void* d_out, int out_size, void* d_ws, size_t ws_size,
                              hipStream_t stream)
{
    const float* input = (const float*)d_in[0];
    const float* W_ih1 = (const float*)d_in[1];
    const float* W_hh1 = (const float*)d_in[2];
    const float* b_ih1 = (const float*)d_in[3];
    const float* b_hh1 = (const float*)d_in[4];
    const float* W_ih2 = (const float*)d_in[5];
    const float* W_hh2 = (const float*)d_in[6];
    const float* b_ih2 = (const float*)d_in[7];
    const float* b_hh2 = (const float*)d_in[8];
    const float* W_lin = (const float*)d_in[9];
    const float* b_lin = (const float*)d_in[10];
    const float* W_o2i = (const float*)d_in[11];
    const float* b_o2i = (const float*)d_in[12];
    float* outp = (float*)d_out;

    char* ws = (char*)d_ws;
    unsigned short* Wcat1 = (unsigned short*)ws; ws += (size_t)4096 * 1088 * 2;
    unsigned short* Wcat2 = (unsigned short*)ws; ws += (size_t)4096 * 2048 * 2;
    unsigned short* Wlinb = (unsigned short*)ws; ws += (size_t)64 * 1024 * 2;
    unsigned short* Wo2ib = (unsigned short*)ws; ws += (size_t)64 * 64 * 2;
    unsigned short* xbf   = (unsigned short*)ws; ws += (size_t)T_SZ * B_SZ * INDIM * 2;
    unsigned short* hh0   = (unsigned short*)ws; ws += (size_t)B_SZ * 2 * HIDN * 2;
    unsigned short* hh1   = (unsigned short*)ws; ws += (size_t)B_SZ * 2 * HIDN * 2;
    float*          c1    = (float*)ws;          ws += (size_t)B_SZ * HIDN * 4;
    float*          c2    = (float*)ws;          ws += (size_t)B_SZ * HIDN * 4;
    unsigned short* xfut  = (unsigned short*)ws; ws += (size_t)B_SZ * INDIM * 2;

    conv_strided<<<(4096 * 64 + 255) / 256, 256, 0, stream>>>(W_ih1, Wcat1, 64, 1088, 0, 4096 * 64);
    conv_strided<<<(4096 * 1024 + 255) / 256, 256, 0, stream>>>(W_hh1, Wcat1, 1024, 1088, 64, 4096 * 1024);
    conv_strided<<<(4096 * 1024 + 255) / 256, 256, 0, stream>>>(W_ih2, Wcat2, 1024, 2048, 0, 4096 * 1024);
    conv_strided<<<(4096 * 1024 + 255) / 256, 256, 0, stream>>>(W_hh2, Wcat2, 1024, 2048, 1024, 4096 * 1024);
    conv_strided<<<(64 * 1024 + 255) / 256, 256, 0, stream>>>(W_lin, Wlinb, 1024, 1024, 0, 64 * 1024);
    conv_strided<<<(64 * 64 + 255) / 256, 256, 0, stream>>>(W_o2i, Wo2ib, 64, 64, 0, 64 * 64);
    conv_x<<<(T_SZ * B_SZ * INDIM) / 256, 256, 0, stream>>>(input, xbf);

    hipMemsetAsync(hh0, 0, (size_t)B_SZ * 2 * HIDN * 2, stream);
    hipMemsetAsync(c1, 0, (size_t)B_SZ * HIDN * 4, stream);
    hipMemsetAsync(c2, 0, (size_t)B_SZ * HIDN * 4, stream);

    void* kargs[] = {
        (void*)&xbf, (void*)&xfut, (void*)&Wcat1, (void*)&Wcat2,
        (void*)&Wlinb, (void*)&Wo2ib,
        (void*)&b_ih1, (void*)&b_hh1, (void*)&b_ih2, (void*)&b_hh2,
        (void*)&b_lin, (void*)&b_o2i,
        (void*)&c1, (void*)&c2, (void*)&hh0, (void*)&hh1, (void*)&outp
    };
    hipLaunchCooperativeKernel((void*)lstm_persist, dim3(256), dim3(512),
                               kargs, 0, stream);
}

// Round 4
// 32370.682 us; speedup vs baseline: 1.1275x; 1.1275x over previous
//
#include <hip/hip_runtime.h>
#include <hip/hip_bf16.h>
#include <hip/hip_cooperative_groups.h>

namespace cg = cooperative_groups;

#define B_SZ   256
#define T_SZ   256
#define FUT    32
#define TF_SZ  (T_SZ + FUT)
#define HIDN   1024
#define INDIM  64
#define OUTDIM 64

typedef __attribute__((ext_vector_type(8))) short bf16x8;
typedef __attribute__((ext_vector_type(4))) float f32x4;

__device__ __forceinline__ float bf2f(unsigned short u) {
    union { unsigned int i; float f; } v; v.i = (unsigned int)u << 16; return v.f;
}
__device__ __forceinline__ unsigned short f2bf(float f) {
    union { float f; unsigned int i; } v; v.f = f;
    unsigned int r = v.i + 0x7FFFu + ((v.i >> 16) & 1u);
    return (unsigned short)(r >> 16);
}
__device__ __forceinline__ float sigm(float x) { return 1.0f / (1.0f + __expf(-x)); }

// ---------------------------------------------------------------------------
// Persistent 2-layer LSTM. Grid 256 x 512 (1 block/CU, 8 waves, 2 waves/SIMD,
// 256-VGPR budget -> weights register-resident WITHOUT spill).
// Block (bg = id&127, bb = id>>7): hidden units [bg*8, bg*8+8) x 4 gates
// (32 gate-rows, A-operand in regs) x batch rows [bb*128, +128).
// Wave ks = K-slice. B-operand (activations) streamed global->VGPR in pairs
// of 16-row fragments; partials reduced via LDS; cell state c in registers.
// ---------------------------------------------------------------------------
__global__ __launch_bounds__(512, 1) __attribute__((amdgpu_waves_per_eu(2, 2)))
void lstm_persist(
    const unsigned short* __restrict__ xbf,    // [256][256][64]
    unsigned short* __restrict__ xfut,         // [256][64]
    const unsigned short* __restrict__ W1,     // [4096][1088]
    const unsigned short* __restrict__ W2,     // [4096][2048]
    const unsigned short* __restrict__ Wlin,   // [64][1024]
    const unsigned short* __restrict__ Wo2i,   // [64][64]
    const float* __restrict__ b_ih1, const float* __restrict__ b_hh1,
    const float* __restrict__ b_ih2, const float* __restrict__ b_hh2,
    const float* __restrict__ blin, const float* __restrict__ bo2i,
    unsigned short* __restrict__ hh0,          // [256][2048] = [h1|h2]
    unsigned short* __restrict__ hh1,
    float* __restrict__ outp)                  // [256][288][64] f32
{
    __shared__ float part[8][32][130];   // [kslice][gate-row][batch col]
    __shared__ float red[512];           // fold partials / phase-3 staging

    cg::grid_group grid = cg::this_grid();

    const int tid  = threadIdx.x;
    const int id   = blockIdx.x;
    const int bg   = id & 127;
    const int bb   = id >> 7;
    const int ks   = tid >> 6;
    const int lane = tid & 63;
    const int am   = lane & 15, ah = lane >> 4;

    // W fragment rows: frag0 = gates i|f, frag1 = gates g|o
    const int wr0 = ((am >> 3)) * 1024 + bg * 8 + (am & 7);
    const int wr1 = (2 + (am >> 3)) * 1024 + bg * 8 + (am & 7);

    // ---- register-resident W (loaded once) ----
    bf16x8 w2r[2][8];
    {
        const size_t b0 = (size_t)wr0 * 2048 + ks * 256 + ah * 8;
        const size_t b1 = (size_t)wr1 * 2048 + ks * 256 + ah * 8;
#pragma unroll
        for (int kk = 0; kk < 8; ++kk) {
            w2r[0][kk] = *(const bf16x8*)(W2 + b0 + kk * 32);
            w2r[1][kk] = *(const bf16x8*)(W2 + b1 + kk * 32);
        }
    }
    const int kb1 = (ks < 2) ? ks * 160 : 320 + (ks - 2) * 128;
    const int kc1 = (ks < 2) ? 5 : 4;
    bf16x8 w1r[2][5];
#pragma unroll
    for (int kk = 0; kk < 5; ++kk) {
        w1r[0][kk] = (bf16x8){0,0,0,0,0,0,0,0};
        w1r[1][kk] = (bf16x8){0,0,0,0,0,0,0,0};
    }
    {
        const size_t b0 = (size_t)wr0 * 1088 + kb1 + ah * 8;
        const size_t b1 = (size_t)wr1 * 1088 + kb1 + ah * 8;
#pragma unroll
        for (int kk = 0; kk < 5; ++kk) if (kk < kc1) {
            w1r[0][kk] = *(const bf16x8*)(W1 + b0 + kk * 32);
            w1r[1][kk] = *(const bf16x8*)(W1 + b1 + kk * 32);
        }
    }

    // ---- epilogue thread constants (t-invariant): cells (j0,brE),(j1,brE) ----
    const int jq0 = tid >> 7;            // 0..3
    const int bl  = tid & 127;
    const int j0  = bg * 8 + jq0, j1 = j0 + 4;
    const int brE = bb * 128 + bl;
    const float b1i0 = b_ih1[j0] + b_hh1[j0];
    const float b1f0 = b_ih1[HIDN + j0] + b_hh1[HIDN + j0];
    const float b1g0 = b_ih1[2*HIDN + j0] + b_hh1[2*HIDN + j0];
    const float b1o0 = b_ih1[3*HIDN + j0] + b_hh1[3*HIDN + j0];
    const float b1i1 = b_ih1[j1] + b_hh1[j1];
    const float b1f1 = b_ih1[HIDN + j1] + b_hh1[HIDN + j1];
    const float b1g1 = b_ih1[2*HIDN + j1] + b_hh1[2*HIDN + j1];
    const float b1o1 = b_ih1[3*HIDN + j1] + b_hh1[3*HIDN + j1];
    const float b2i0 = b_ih2[j0] + b_hh2[j0];
    const float b2f0 = b_ih2[HIDN + j0] + b_hh2[HIDN + j0];
    const float b2g0 = b_ih2[2*HIDN + j0] + b_hh2[2*HIDN + j0];
    const float b2o0 = b_ih2[3*HIDN + j0] + b_hh2[3*HIDN + j0];
    const float b2i1 = b_ih2[j1] + b_hh2[j1];
    const float b2f1 = b_ih2[HIDN + j1] + b_hh2[HIDN + j1];
    const float b2g1 = b_ih2[2*HIDN + j1] + b_hh2[2*HIDN + j1];
    const float b2o1 = b_ih2[3*HIDN + j1] + b_hh2[3*HIDN + j1];
    float c1a = 0.f, c1b = 0.f, c2a = 0.f, c2b = 0.f;  // cell state in regs

    // ---- fold (out(t-1)) constants: block -> (col, row quarter) ----
    const int fc = id & 63;
    const int fq = id >> 6;
    const int fr = fq * 64 + (tid >> 3);
    const int fk = (tid & 7) * 128;

    for (int t = 0; t < TF_SZ; ++t) {
        const unsigned short* hsrc = (t & 1) ? hh1 : hh0;
        unsigned short*       hdst = (t & 1) ? hh0 : hh1;
        const unsigned short* xsrc = (t < T_SZ) ? (xbf + (size_t)t * B_SZ * INDIM) : xfut;

        // ===== phase 1: fold out(t-1) + layer-1 gates + cell =====
        if (t >= 1 && t <= 255) {
            const unsigned short* hp = hsrc + (size_t)fr * 2048 + 1024 + fk;
            const unsigned short* wp = Wlin + (size_t)fc * 1024 + fk;
            float p = 0.f;
#pragma unroll
            for (int k = 0; k < 128; k += 8) {
                bf16x8 hv = *(const bf16x8*)(hp + k);
                bf16x8 wv = *(const bf16x8*)(wp + k);
#pragma unroll
                for (int u = 0; u < 8; ++u)
                    p += bf2f((unsigned short)hv[u]) * bf2f((unsigned short)wv[u]);
            }
            red[tid] = p;           // tid = (row_local<<3)|kq
            __syncthreads();
            if (tid < 64) {
                float s = blin[fc];
#pragma unroll
                for (int u = 0; u < 8; ++u) s += red[tid * 8 + u];
                outp[((size_t)(fq * 64 + tid) * TF_SZ + (t - 1)) * OUTDIM + fc] = s;
            }
            __syncthreads();
        }

        // layer-1 gates: stream batch frags in pairs (keeps regs bounded)
#pragma unroll 1
        for (int np = 0; np < 8; np += 2) {
            const int brow0 = bb * 128 + np * 16 + am;
            const int brow1 = brow0 + 16;
            bf16x8 f0[5], f1[5];
#pragma unroll
            for (int kk = 0; kk < 5; ++kk) if (kk < kc1) {
                const int k = kb1 + kk * 32 + ah * 8;
                if (k < 64) {
                    f0[kk] = *(const bf16x8*)(xsrc + (size_t)brow0 * INDIM + k);
                    f1[kk] = *(const bf16x8*)(xsrc + (size_t)brow1 * INDIM + k);
                } else {
                    f0[kk] = *(const bf16x8*)(hsrc + (size_t)brow0 * 2048 + (k - 64));
                    f1[kk] = *(const bf16x8*)(hsrc + (size_t)brow1 * 2048 + (k - 64));
                }
            }
            f32x4 p00 = {0,0,0,0}, p01 = {0,0,0,0}, p10 = {0,0,0,0}, p11 = {0,0,0,0};
#pragma unroll
            for (int kk = 0; kk < 5; ++kk) if (kk < kc1) {
                p00 = __builtin_amdgcn_mfma_f32_16x16x32_bf16(w1r[0][kk], f0[kk], p00, 0, 0, 0);
                p01 = __builtin_amdgcn_mfma_f32_16x16x32_bf16(w1r[1][kk], f0[kk], p01, 0, 0, 0);
                p10 = __builtin_amdgcn_mfma_f32_16x16x32_bf16(w1r[0][kk], f1[kk], p10, 0, 0, 0);
                p11 = __builtin_amdgcn_mfma_f32_16x16x32_bf16(w1r[1][kk], f1[kk], p11, 0, 0, 0);
            }
#pragma unroll
            for (int r = 0; r < 4; ++r) {
                part[ks][ah * 4 + r][np * 16 + am]            = p00[r];
                part[ks][16 + ah * 4 + r][np * 16 + am]       = p01[r];
                part[ks][ah * 4 + r][(np + 1) * 16 + am]      = p10[r];
                part[ks][16 + ah * 4 + r][(np + 1) * 16 + am] = p11[r];
            }
        }
        __syncthreads();
        {   // cell update (j0, brE)
            float g0 = 0.f, g1 = 0.f, g2 = 0.f, g3 = 0.f;
#pragma unroll
            for (int s = 0; s < 8; ++s) {
                g0 += part[s][jq0][bl];      g1 += part[s][8 + jq0][bl];
                g2 += part[s][16 + jq0][bl]; g3 += part[s][24 + jq0][bl];
            }
            const float gi = sigm(g0 + b1i0), gf = sigm(g1 + b1f0);
            const float gg = tanhf(g2 + b1g0), go = sigm(g3 + b1o0);
            c1a = gf * c1a + gi * gg;
            hdst[(size_t)brE * 2048 + j0] = f2bf(go * tanhf(c1a));
        }
        {   // cell update (j1, brE)
            float g0 = 0.f, g1 = 0.f, g2 = 0.f, g3 = 0.f;
#pragma unroll
            for (int s = 0; s < 8; ++s) {
                g0 += part[s][4 + jq0][bl];  g1 += part[s][12 + jq0][bl];
                g2 += part[s][20 + jq0][bl]; g3 += part[s][28 + jq0][bl];
            }
            const float gi = sigm(g0 + b1i1), gf = sigm(g1 + b1f1);
            const float gg = tanhf(g2 + b1g1), go = sigm(g3 + b1o1);
            c1b = gf * c1b + gi * gg;
            hdst[(size_t)brE * 2048 + j1] = f2bf(go * tanhf(c1b));
        }
        grid.sync();

        // ===== phase 2: layer-2 gates + cell =====
        {
            const unsigned short* hb = (ks < 4) ? hdst : hsrc;   // h1(t) | h2(t-1)
#pragma unroll 1
            for (int np = 0; np < 8; np += 2) {
                const int brow0 = bb * 128 + np * 16 + am;
                const int brow1 = brow0 + 16;
                const unsigned short* bp0 = hb + (size_t)brow0 * 2048 + ks * 256 + ah * 8;
                const unsigned short* bp1 = hb + (size_t)brow1 * 2048 + ks * 256 + ah * 8;
                bf16x8 f0[8], f1[8];
#pragma unroll
                for (int kk = 0; kk < 8; ++kk) {
                    f0[kk] = *(const bf16x8*)(bp0 + kk * 32);
                    f1[kk] = *(const bf16x8*)(bp1 + kk * 32);
                }
                f32x4 p00 = {0,0,0,0}, p01 = {0,0,0,0}, p10 = {0,0,0,0}, p11 = {0,0,0,0};
#pragma unroll
                for (int kk = 0; kk < 8; ++kk) {
                    p00 = __builtin_amdgcn_mfma_f32_16x16x32_bf16(w2r[0][kk], f0[kk], p00, 0, 0, 0);
                    p01 = __builtin_amdgcn_mfma_f32_16x16x32_bf16(w2r[1][kk], f0[kk], p01, 0, 0, 0);
                    p10 = __builtin_amdgcn_mfma_f32_16x16x32_bf16(w2r[0][kk], f1[kk], p10, 0, 0, 0);
                    p11 = __builtin_amdgcn_mfma_f32_16x16x32_bf16(w2r[1][kk], f1[kk], p11, 0, 0, 0);
                }
#pragma unroll
                for (int r = 0; r < 4; ++r) {
                    part[ks][ah * 4 + r][np * 16 + am]            = p00[r];
                    part[ks][16 + ah * 4 + r][np * 16 + am]       = p01[r];
                    part[ks][ah * 4 + r][(np + 1) * 16 + am]      = p10[r];
                    part[ks][16 + ah * 4 + r][(np + 1) * 16 + am] = p11[r];
                }
            }
        }
        __syncthreads();
        {
            float g0 = 0.f, g1 = 0.f, g2 = 0.f, g3 = 0.f;
#pragma unroll
            for (int s = 0; s < 8; ++s) {
                g0 += part[s][jq0][bl];      g1 += part[s][8 + jq0][bl];
                g2 += part[s][16 + jq0][bl]; g3 += part[s][24 + jq0][bl];
            }
            const float gi = sigm(g0 + b2i0), gf = sigm(g1 + b2f0);
            const float gg = tanhf(g2 + b2g0), go = sigm(g3 + b2o0);
            c2a = gf * c2a + gi * gg;
            hdst[(size_t)brE * 2048 + 1024 + j0] = f2bf(go * tanhf(c2a));
        }
        {
            float g0 = 0.f, g1 = 0.f, g2 = 0.f, g3 = 0.f;
#pragma unroll
            for (int s = 0; s < 8; ++s) {
                g0 += part[s][4 + jq0][bl];  g1 += part[s][12 + jq0][bl];
                g2 += part[s][20 + jq0][bl]; g3 += part[s][28 + jq0][bl];
            }
            const float gi = sigm(g0 + b2i1), gf = sigm(g1 + b2f1);
            const float gg = tanhf(g2 + b2g1), go = sigm(g3 + b2o1);
            c2b = gf * c2b + gi * gg;
            hdst[(size_t)brE * 2048 + 1024 + j1] = f2bf(go * tanhf(c2b));
        }
        grid.sync();

        // ===== phase 3 (t>=255): out(t) + feedback x(t+1) =====
        if (t >= T_SZ - 1) {
            if (id < 32) {
                unsigned short* h2s = (unsigned short*)&part[0][0][0];  // [8][1024]
                const int rowbase = id * 8;
                for (int i = tid; i < 1024; i += 512) {
                    const int rr = i >> 7, k8 = (i & 127) * 8;
                    *(bf16x8*)&h2s[rr * 1024 + k8] =
                        *(const bf16x8*)&hdst[(size_t)(rowbase + rr) * 2048 + 1024 + k8];
                }
                __syncthreads();
                const int rl = tid >> 6, col = tid & 63;
                float acc = blin[col];
                const unsigned short* wl = Wlin + (size_t)col * HIDN;
                for (int k = 0; k < HIDN; k += 8) {
                    bf16x8 hv = *(const bf16x8*)&h2s[rl * 1024 + k];
                    bf16x8 wv = *(const bf16x8*)&wl[k];
#pragma unroll
                    for (int u = 0; u < 8; ++u)
                        acc += bf2f((unsigned short)hv[u]) * bf2f((unsigned short)wv[u]);
                }
                outp[((size_t)(rowbase + rl) * TF_SZ + t) * OUTDIM + col] = acc;
                if (t < TF_SZ - 1) {
                    red[rl * 64 + col] = acc;
                    __syncthreads();
                    float x = bo2i[col];
                    const unsigned short* w2 = Wo2i + (size_t)col * OUTDIM;
#pragma unroll 8
                    for (int jj = 0; jj < OUTDIM; ++jj)
                        x += red[rl * 64 + jj] * bf2f(w2[jj]);
                    xfut[(size_t)(rowbase + rl) * INDIM + col] = f2bf(x);
                }
            }
            grid.sync();
        }
    }
}

__global__ void conv_strided(const float* __restrict__ src,
                             unsigned short* __restrict__ dst,
                             int cols, int dstride, int doff, int total)
{
    const int idx = blockIdx.x * 256 + threadIdx.x;
    if (idx >= total) return;
    const int r = idx / cols, c = idx - r * cols;
    dst[(size_t)r * dstride + doff + c] = f2bf(src[idx]);
}

__global__ void conv_x(const float* __restrict__ src,
                       unsigned short* __restrict__ dst)
{
    const int idx = blockIdx.x * 256 + threadIdx.x;
    const int f = idx & 63, t = (idx >> 6) & 255, b = idx >> 14;
    dst[((size_t)t * B_SZ + b) * INDIM + f] = f2bf(src[idx]);
}

extern "C" void kernel_launch(void* const* d_in, const int* in_sizes, int n_in,
                              void* d_out, int out_size, void* d_ws, size_t ws_size,
                              hipStream_t stream)
{
    const float* input = (const float*)d_in[0];
    const float* W_ih1 = (const float*)d_in[1];
    const float* W_hh1 = (const float*)d_in[2];
    const float* b_ih1 = (const float*)d_in[3];
    const float* b_hh1 = (const float*)d_in[4];
    const float* W_ih2 = (const float*)d_in[5];
    const float* W_hh2 = (const float*)d_in[6];
    const float* b_ih2 = (const float*)d_in[7];
    const float* b_hh2 = (const float*)d_in[8];
    const float* W_lin = (const float*)d_in[9];
    const float* b_lin = (const float*)d_in[10];
    const float* W_o2i = (const float*)d_in[11];
    const float* b_o2i = (const float*)d_in[12];
    float* outp = (float*)d_out;

    char* ws = (char*)d_ws;
    unsigned short* Wcat1 = (unsigned short*)ws; ws += (size_t)4096 * 1088 * 2;
    unsigned short* Wcat2 = (unsigned short*)ws; ws += (size_t)4096 * 2048 * 2;
    unsigned short* Wlinb = (unsigned short*)ws; ws += (size_t)64 * 1024 * 2;
    unsigned short* Wo2ib = (unsigned short*)ws; ws += (size_t)64 * 64 * 2;
    unsigned short* xbf   = (unsigned short*)ws; ws += (size_t)T_SZ * B_SZ * INDIM * 2;
    unsigned short* hh0   = (unsigned short*)ws; ws += (size_t)B_SZ * 2 * HIDN * 2;
    unsigned short* hh1   = (unsigned short*)ws; ws += (size_t)B_SZ * 2 * HIDN * 2;
    unsigned short* xfut  = (unsigned short*)ws; ws += (size_t)B_SZ * INDIM * 2;

    conv_strided<<<(4096 * 64 + 255) / 256, 256, 0, stream>>>(W_ih1, Wcat1, 64, 1088, 0, 4096 * 64);
    conv_strided<<<(4096 * 1024 + 255) / 256, 256, 0, stream>>>(W_hh1, Wcat1, 1024, 1088, 64, 4096 * 1024);
    conv_strided<<<(4096 * 1024 + 255) / 256, 256, 0, stream>>>(W_ih2, Wcat2, 1024, 2048, 0, 4096 * 1024);
    conv_strided<<<(4096 * 1024 + 255) / 256, 256, 0, stream>>>(W_hh2, Wcat2, 1024, 2048, 1024, 4096 * 1024);
    conv_strided<<<(64 * 1024 + 255) / 256, 256, 0, stream>>>(W_lin, Wlinb, 1024, 1024, 0, 64 * 1024);
    conv_strided<<<(64 * 64 + 255) / 256, 256, 0, stream>>>(W_o2i, Wo2ib, 64, 64, 0, 64 * 64);
    conv_x<<<(T_SZ * B_SZ * INDIM) / 256, 256, 0, stream>>>(input, xbf);

    hipMemsetAsync(hh0, 0, (size_t)B_SZ * 2 * HIDN * 2, stream);

    void* kargs[] = {
        (void*)&xbf, (void*)&xfut, (void*)&Wcat1, (void*)&Wcat2,
        (void*)&Wlinb, (void*)&Wo2ib,
        (void*)&b_ih1, (void*)&b_hh1, (void*)&b_ih2, (void*)&b_hh2,
        (void*)&b_lin, (void*)&b_o2i,
        (void*)&hh0, (void*)&hh1, (void*)&outp
    };
    hipLaunchCooperativeKernel((void*)lstm_persist, dim3(256), dim3(512),
                               kargs, 0, stream);
}

// Round 5
// 28509.280 us; speedup vs baseline: 1.2802x; 1.1354x over previous
//
#include <hip/hip_runtime.h>
#include <hip/hip_bf16.h>

#define B_SZ   256
#define T_SZ   256
#define FUT    32
#define TF_SZ  (T_SZ + FUT)
#define HIDN   1024
#define INDIM  64
#define OUTDIM 64
#define NBLK   256

typedef __attribute__((ext_vector_type(8))) short bf16x8;
typedef __attribute__((ext_vector_type(4))) float f32x4;

__device__ __forceinline__ float bf2f(unsigned short u) {
    union { unsigned int i; float f; } v; v.i = (unsigned int)u << 16; return v.f;
}
__device__ __forceinline__ unsigned short f2bf(float f) {
    union { float f; unsigned int i; } v; v.f = f;
    unsigned int r = v.i + 0x7FFFu + ((v.i >> 16) & 1u);
    return (unsigned short)(r >> 16);
}
__device__ __forceinline__ float sigm(float x) { return 1.0f / (1.0f + __expf(-x)); }

// Lightweight device-scope grid barrier (sense-reversing, sleep backoff).
// bar[0] = arrive counter, bar[1] = generation. Memset to 0 per launch.
__device__ __forceinline__ void grid_barrier(unsigned int* bar) {
    __syncthreads();
    if (threadIdx.x == 0) {
        __builtin_amdgcn_fence(__ATOMIC_RELEASE, "agent");     // release h writes
        unsigned int gen = __hip_atomic_load(&bar[1], __ATOMIC_ACQUIRE,
                                             __HIP_MEMORY_SCOPE_AGENT);
        unsigned int a = __hip_atomic_fetch_add(&bar[0], 1u, __ATOMIC_RELAXED,
                                                __HIP_MEMORY_SCOPE_AGENT);
        if (a == NBLK - 1) {
            __hip_atomic_store(&bar[0], 0u, __ATOMIC_RELAXED,
                               __HIP_MEMORY_SCOPE_AGENT);
            __hip_atomic_store(&bar[1], gen + 1u, __ATOMIC_RELEASE,
                               __HIP_MEMORY_SCOPE_AGENT);
        } else {
            while (__hip_atomic_load(&bar[1], __ATOMIC_RELAXED,
                                     __HIP_MEMORY_SCOPE_AGENT) == gen)
                __builtin_amdgcn_s_sleep(2);
        }
        __builtin_amdgcn_fence(__ATOMIC_ACQUIRE, "agent");     // acquire others'
    }
    __syncthreads();
}

// ---------------------------------------------------------------------------
// Persistent 2-layer LSTM. Grid 256 x 512 (1 block/CU, 8 waves, 2 waves/SIMD,
// 256-VGPR budget -> weights register-resident).
// Block (bg = id&127, bb = id>>7): hidden units [bg*8, +8) x 4 gates
// (32 gate-rows, A-operand in regs) x batch rows [bb*128, +128).
// Wave ks = K-slice. B-operand streamed global->VGPR in fragment pairs;
// partials reduced via LDS; cell state c in registers; biases in LDS.
// ---------------------------------------------------------------------------
__global__ __attribute__((amdgpu_flat_work_group_size(512, 512),
                          amdgpu_waves_per_eu(2, 2)))
void lstm_persist(
    const unsigned short* __restrict__ xbf,    // [256][256][64]
    unsigned short* __restrict__ xfut,         // [256][64]
    const unsigned short* __restrict__ W1,     // [4096][1088]
    const unsigned short* __restrict__ W2,     // [4096][2048]
    const unsigned short* __restrict__ Wlin,   // [64][1024]
    const unsigned short* __restrict__ Wo2i,   // [64][64]
    const float* __restrict__ b_ih1, const float* __restrict__ b_hh1,
    const float* __restrict__ b_ih2, const float* __restrict__ b_hh2,
    const float* __restrict__ blin, const float* __restrict__ bo2i,
    unsigned short* __restrict__ hh0,          // [256][2048] = [h1|h2]
    unsigned short* __restrict__ hh1,
    float* __restrict__ outp,                  // [256][288][64] f32
    unsigned int* __restrict__ bar)
{
    __shared__ float part[8][32][130];   // [kslice][gate-row][batch col]
    __shared__ float red[512];           // fold partials / phase-3 staging
    __shared__ float blds[64];           // biases: [layer][gate][unit] = L*32+G*8+q

    const int tid  = threadIdx.x;
    const int id   = blockIdx.x;
    const int bg   = id & 127;
    const int bb   = id >> 7;
    const int ks   = tid >> 6;
    const int lane = tid & 63;
    const int am   = lane & 15, ah = lane >> 4;

    // biases -> LDS (once)
    if (tid < 64) {
        const int L = tid >> 5, G = (tid >> 3) & 3, q = tid & 7;
        const int j = bg * 8 + q;
        blds[tid] = L ? (b_ih2[G * HIDN + j] + b_hh2[G * HIDN + j])
                      : (b_ih1[G * HIDN + j] + b_hh1[G * HIDN + j]);
    }

    // W fragment rows: frag0 = gates i|f, frag1 = gates g|o
    const int wr0 = ((am >> 3)) * 1024 + bg * 8 + (am & 7);
    const int wr1 = (2 + (am >> 3)) * 1024 + bg * 8 + (am & 7);

    // ---- register-resident W (loaded once) ----
    bf16x8 w2r[2][8];
    {
        const size_t b0 = (size_t)wr0 * 2048 + ks * 256 + ah * 8;
        const size_t b1 = (size_t)wr1 * 2048 + ks * 256 + ah * 8;
#pragma unroll
        for (int kk = 0; kk < 8; ++kk) {
            w2r[0][kk] = *(const bf16x8*)(W2 + b0 + kk * 32);
            w2r[1][kk] = *(const bf16x8*)(W2 + b1 + kk * 32);
        }
    }
    const int kb1 = (ks < 2) ? ks * 160 : 320 + (ks - 2) * 128;
    const int kc1 = (ks < 2) ? 5 : 4;
    bf16x8 w1r[2][5];
#pragma unroll
    for (int kk = 0; kk < 5; ++kk) {
        w1r[0][kk] = (bf16x8){0,0,0,0,0,0,0,0};
        w1r[1][kk] = (bf16x8){0,0,0,0,0,0,0,0};
    }
    {
        const size_t b0 = (size_t)wr0 * 1088 + kb1 + ah * 8;
        const size_t b1 = (size_t)wr1 * 1088 + kb1 + ah * 8;
#pragma unroll
        for (int kk = 0; kk < 5; ++kk) if (kk < kc1) {
            w1r[0][kk] = *(const bf16x8*)(W1 + b0 + kk * 32);
            w1r[1][kk] = *(const bf16x8*)(W1 + b1 + kk * 32);
        }
    }

    // epilogue constants: cells (j0,brE),(j1,brE); c state in regs
    const int jq0 = tid >> 7;            // 0..3
    const int bl  = tid & 127;
    const int j0  = bg * 8 + jq0, j1 = j0 + 4;
    const int brE = bb * 128 + bl;
    float c1a = 0.f, c1b = 0.f, c2a = 0.f, c2b = 0.f;

    // fold constants: block -> (col fc, row quarter fq); thread -> (row, kq)
    const int fc = id & 63;
    const int fq = id >> 6;
    const int frow = tid & 63;           // row within quarter
    const int fkq  = tid >> 6;           // 0..7, K-slice of 128
    __syncthreads();                     // blds visible

    for (int t = 0; t < TF_SZ; ++t) {
        const unsigned short* hsrc = (t & 1) ? hh1 : hh0;
        unsigned short*       hdst = (t & 1) ? hh0 : hh1;
        const unsigned short* xsrc = (t < T_SZ) ? (xbf + (size_t)t * B_SZ * INDIM) : xfut;

        // ===== phase 1: fold out(t-1) + layer-1 gates + cell =====
        if (t >= 1 && t <= 255) {
            const unsigned short* hp = hsrc + (size_t)(fq * 64 + frow) * 2048 + 1024 + fkq * 128;
            const unsigned short* wp = Wlin + (size_t)fc * 1024 + fkq * 128;
            float p = 0.f;
#pragma unroll
            for (int k = 0; k < 128; k += 8) {
                bf16x8 hv = *(const bf16x8*)(hp + k);
                bf16x8 wv = *(const bf16x8*)(wp + k);
#pragma unroll
                for (int u = 0; u < 8; ++u)
                    p += bf2f((unsigned short)hv[u]) * bf2f((unsigned short)wv[u]);
            }
            red[fkq * 64 + frow] = p;            // stride-1, conflict-free
            __syncthreads();
            if (tid < 64) {
                float s = blin[fc];
#pragma unroll
                for (int u = 0; u < 8; ++u) s += red[u * 64 + tid];
                outp[((size_t)(fq * 64 + tid) * TF_SZ + (t - 1)) * OUTDIM + fc] = s;
            }
            __syncthreads();
        }

        // layer-1 gates: stream batch frags in pairs
#pragma unroll 1
        for (int np = 0; np < 8; np += 2) {
            const int brow0 = bb * 128 + np * 16 + am;
            const int brow1 = brow0 + 16;
            bf16x8 f0[5], f1[5];
#pragma unroll
            for (int kk = 0; kk < 5; ++kk) if (kk < kc1) {
                const int k = kb1 + kk * 32 + ah * 8;
                if (k < 64) {
                    f0[kk] = *(const bf16x8*)(xsrc + (size_t)brow0 * INDIM + k);
                    f1[kk] = *(const bf16x8*)(xsrc + (size_t)brow1 * INDIM + k);
                } else {
                    f0[kk] = *(const bf16x8*)(hsrc + (size_t)brow0 * 2048 + (k - 64));
                    f1[kk] = *(const bf16x8*)(hsrc + (size_t)brow1 * 2048 + (k - 64));
                }
            }
            f32x4 p00 = {0,0,0,0}, p01 = {0,0,0,0}, p10 = {0,0,0,0}, p11 = {0,0,0,0};
#pragma unroll
            for (int kk = 0; kk < 5; ++kk) if (kk < kc1) {
                p00 = __builtin_amdgcn_mfma_f32_16x16x32_bf16(w1r[0][kk], f0[kk], p00, 0, 0, 0);
                p01 = __builtin_amdgcn_mfma_f32_16x16x32_bf16(w1r[1][kk], f0[kk], p01, 0, 0, 0);
                p10 = __builtin_amdgcn_mfma_f32_16x16x32_bf16(w1r[0][kk], f1[kk], p10, 0, 0, 0);
                p11 = __builtin_amdgcn_mfma_f32_16x16x32_bf16(w1r[1][kk], f1[kk], p11, 0, 0, 0);
            }
#pragma unroll
            for (int r = 0; r < 4; ++r) {
                part[ks][ah * 4 + r][np * 16 + am]            = p00[r];
                part[ks][16 + ah * 4 + r][np * 16 + am]       = p01[r];
                part[ks][ah * 4 + r][(np + 1) * 16 + am]      = p10[r];
                part[ks][16 + ah * 4 + r][(np + 1) * 16 + am] = p11[r];
            }
        }
        __syncthreads();
        {   // cell (j0, brE)
            float g0 = 0.f, g1 = 0.f, g2 = 0.f, g3 = 0.f;
#pragma unroll
            for (int s = 0; s < 8; ++s) {
                g0 += part[s][jq0][bl];      g1 += part[s][8 + jq0][bl];
                g2 += part[s][16 + jq0][bl]; g3 += part[s][24 + jq0][bl];
            }
            const float gi = sigm(g0 + blds[jq0]), gf = sigm(g1 + blds[8 + jq0]);
            const float gg = tanhf(g2 + blds[16 + jq0]), go = sigm(g3 + blds[24 + jq0]);
            c1a = gf * c1a + gi * gg;
            hdst[(size_t)brE * 2048 + j0] = f2bf(go * tanhf(c1a));
        }
        {   // cell (j1, brE)
            float g0 = 0.f, g1 = 0.f, g2 = 0.f, g3 = 0.f;
#pragma unroll
            for (int s = 0; s < 8; ++s) {
                g0 += part[s][4 + jq0][bl];  g1 += part[s][12 + jq0][bl];
                g2 += part[s][20 + jq0][bl]; g3 += part[s][28 + jq0][bl];
            }
            const float gi = sigm(g0 + blds[4 + jq0]), gf = sigm(g1 + blds[12 + jq0]);
            const float gg = tanhf(g2 + blds[20 + jq0]), go = sigm(g3 + blds[28 + jq0]);
            c1b = gf * c1b + gi * gg;
            hdst[(size_t)brE * 2048 + j1] = f2bf(go * tanhf(c1b));
        }
        grid_barrier(bar);

        // ===== phase 2: layer-2 gates + cell =====
        {
            const unsigned short* hb = (ks < 4) ? hdst : hsrc;   // h1(t) | h2(t-1)
#pragma unroll 1
            for (int np = 0; np < 8; np += 2) {
                const int brow0 = bb * 128 + np * 16 + am;
                const int brow1 = brow0 + 16;
                const unsigned short* bp0 = hb + (size_t)brow0 * 2048 + ks * 256 + ah * 8;
                const unsigned short* bp1 = hb + (size_t)brow1 * 2048 + ks * 256 + ah * 8;
                bf16x8 f0[8], f1[8];
#pragma unroll
                for (int kk = 0; kk < 8; ++kk) {
                    f0[kk] = *(const bf16x8*)(bp0 + kk * 32);
                    f1[kk] = *(const bf16x8*)(bp1 + kk * 32);
                }
                f32x4 p00 = {0,0,0,0}, p01 = {0,0,0,0}, p10 = {0,0,0,0}, p11 = {0,0,0,0};
#pragma unroll
                for (int kk = 0; kk < 8; ++kk) {
                    p00 = __builtin_amdgcn_mfma_f32_16x16x32_bf16(w2r[0][kk], f0[kk], p00, 0, 0, 0);
                    p01 = __builtin_amdgcn_mfma_f32_16x16x32_bf16(w2r[1][kk], f0[kk], p01, 0, 0, 0);
                    p10 = __builtin_amdgcn_mfma_f32_16x16x32_bf16(w2r[0][kk], f1[kk], p10, 0, 0, 0);
                    p11 = __builtin_amdgcn_mfma_f32_16x16x32_bf16(w2r[1][kk], f1[kk], p11, 0, 0, 0);
                }
#pragma unroll
                for (int r = 0; r < 4; ++r) {
                    part[ks][ah * 4 + r][np * 16 + am]            = p00[r];
                    part[ks][16 + ah * 4 + r][np * 16 + am]       = p01[r];
                    part[ks][ah * 4 + r][(np + 1) * 16 + am]      = p10[r];
                    part[ks][16 + ah * 4 + r][(np + 1) * 16 + am] = p11[r];
                }
            }
        }
        __syncthreads();
        {
            float g0 = 0.f, g1 = 0.f, g2 = 0.f, g3 = 0.f;
#pragma unroll
            for (int s = 0; s < 8; ++s) {
                g0 += part[s][jq0][bl];      g1 += part[s][8 + jq0][bl];
                g2 += part[s][16 + jq0][bl]; g3 += part[s][24 + jq0][bl];
            }
            const float gi = sigm(g0 + blds[32 + jq0]), gf = sigm(g1 + blds[40 + jq0]);
            const float gg = tanhf(g2 + blds[48 + jq0]), go = sigm(g3 + blds[56 + jq0]);
            c2a = gf * c2a + gi * gg;
            hdst[(size_t)brE * 2048 + 1024 + j0] = f2bf(go * tanhf(c2a));
        }
        {
            float g0 = 0.f, g1 = 0.f, g2 = 0.f, g3 = 0.f;
#pragma unroll
            for (int s = 0; s < 8; ++s) {
                g0 += part[s][4 + jq0][bl];  g1 += part[s][12 + jq0][bl];
                g2 += part[s][20 + jq0][bl]; g3 += part[s][28 + jq0][bl];
            }
            const float gi = sigm(g0 + blds[36 + jq0]), gf = sigm(g1 + blds[44 + jq0]);
            const float gg = tanhf(g2 + blds[52 + jq0]), go = sigm(g3 + blds[60 + jq0]);
            c2b = gf * c2b + gi * gg;
            hdst[(size_t)brE * 2048 + 1024 + j1] = f2bf(go * tanhf(c2b));
        }
        grid_barrier(bar);

        // ===== phase 3 (t>=255): out(t) + feedback x(t+1) =====
        if (t >= T_SZ - 1) {
            if (id < 32) {
                unsigned short* h2s = (unsigned short*)&part[0][0][0];  // [8][1024]
                const int rowbase = id * 8;
                for (int i = tid; i < 1024; i += 512) {
                    const int rr = i >> 7, k8 = (i & 127) * 8;
                    *(bf16x8*)&h2s[rr * 1024 + k8] =
                        *(const bf16x8*)&hdst[(size_t)(rowbase + rr) * 2048 + 1024 + k8];
                }
                __syncthreads();
                const int rl = tid >> 6, col = tid & 63;
                float acc = blin[col];
                const unsigned short* wl = Wlin + (size_t)col * HIDN;
                for (int k = 0; k < HIDN; k += 8) {
                    bf16x8 hv = *(const bf16x8*)&h2s[rl * 1024 + k];
                    bf16x8 wv = *(const bf16x8*)&wl[k];
#pragma unroll
                    for (int u = 0; u < 8; ++u)
                        acc += bf2f((unsigned short)hv[u]) * bf2f((unsigned short)wv[u]);
                }
                outp[((size_t)(rowbase + rl) * TF_SZ + t) * OUTDIM + col] = acc;
                if (t < TF_SZ - 1) {
                    red[rl * 64 + col] = acc;
                    __syncthreads();
                    float x = bo2i[col];
                    const unsigned short* w2 = Wo2i + (size_t)col * OUTDIM;
#pragma unroll 8
                    for (int jj = 0; jj < OUTDIM; ++jj)
                        x += red[rl * 64 + jj] * bf2f(w2[jj]);
                    xfut[(size_t)(rowbase + rl) * INDIM + col] = f2bf(x);
                }
            }
            grid_barrier(bar);
        }
    }
}

__global__ void conv_strided(const float* __restrict__ src,
                             unsigned short* __restrict__ dst,
                             int cols, int dstride, int doff, int total)
{
    const int idx = blockIdx.x * 256 + threadIdx.x;
    if (idx >= total) return;
    const int r = idx / cols, c = idx - r * cols;
    dst[(size_t)r * dstride + doff + c] = f2bf(src[idx]);
}

__global__ void conv_x(const float* __restrict__ src,
                       unsigned short* __restrict__ dst)
{
    const int idx = blockIdx.x * 256 + threadIdx.x;
    const int f = idx & 63, t = (idx >> 6) & 255, b = idx >> 14;
    dst[((size_t)t * B_SZ + b) * INDIM + f] = f2bf(src[idx]);
}

extern "C" void kernel_launch(void* const* d_in, const int* in_sizes, int n_in,
                              void* d_out, int out_size, void* d_ws, size_t ws_size,
                              hipStream_t stream)
{
    const float* input = (const float*)d_in[0];
    const float* W_ih1 = (const float*)d_in[1];
    const float* W_hh1 = (const float*)d_in[2];
    const float* b_ih1 = (const float*)d_in[3];
    const float* b_hh1 = (const float*)d_in[4];
    const float* W_ih2 = (const float*)d_in[5];
    const float* W_hh2 = (const float*)d_in[6];
    const float* b_ih2 = (const float*)d_in[7];
    const float* b_hh2 = (const float*)d_in[8];
    const float* W_lin = (const float*)d_in[9];
    const float* b_lin = (const float*)d_in[10];
    const float* W_o2i = (const float*)d_in[11];
    const float* b_o2i = (const float*)d_in[12];
    float* outp = (float*)d_out;

    char* ws = (char*)d_ws;
    unsigned short* Wcat1 = (unsigned short*)ws; ws += (size_t)4096 * 1088 * 2;
    unsigned short* Wcat2 = (unsigned short*)ws; ws += (size_t)4096 * 2048 * 2;
    unsigned short* Wlinb = (unsigned short*)ws; ws += (size_t)64 * 1024 * 2;
    unsigned short* Wo2ib = (unsigned short*)ws; ws += (size_t)64 * 64 * 2;
    unsigned short* xbf   = (unsigned short*)ws; ws += (size_t)T_SZ * B_SZ * INDIM * 2;
    unsigned short* hh0   = (unsigned short*)ws; ws += (size_t)B_SZ * 2 * HIDN * 2;
    unsigned short* hh1   = (unsigned short*)ws; ws += (size_t)B_SZ * 2 * HIDN * 2;
    unsigned short* xfut  = (unsigned short*)ws; ws += (size_t)B_SZ * INDIM * 2;
    ws = (char*)(((size_t)ws + 127) & ~(size_t)127);
    unsigned int*   bar   = (unsigned int*)ws;   ws += 128;

    conv_strided<<<(4096 * 64 + 255) / 256, 256, 0, stream>>>(W_ih1, Wcat1, 64, 1088, 0, 4096 * 64);
    conv_strided<<<(4096 * 1024 + 255) / 256, 256, 0, stream>>>(W_hh1, Wcat1, 1024, 1088, 64, 4096 * 1024);
    conv_strided<<<(4096 * 1024 + 255) / 256, 256, 0, stream>>>(W_ih2, Wcat2, 1024, 2048, 0, 4096 * 1024);
    conv_strided<<<(4096 * 1024 + 255) / 256, 256, 0, stream>>>(W_hh2, Wcat2, 1024, 2048, 1024, 4096 * 1024);
    conv_strided<<<(64 * 1024 + 255) / 256, 256, 0, stream>>>(W_lin, Wlinb, 1024, 1024, 0, 64 * 1024);
    conv_strided<<<(64 * 64 + 255) / 256, 256, 0, stream>>>(W_o2i, Wo2ib, 64, 64, 0, 64 * 64);
    conv_x<<<(T_SZ * B_SZ * INDIM) / 256, 256, 0, stream>>>(input, xbf);

    hipMemsetAsync(hh0, 0, (size_t)B_SZ * 2 * HIDN * 2, stream);
    hipMemsetAsync(bar, 0, 128, stream);

    void* kargs[] = {
        (void*)&xbf, (void*)&xfut, (void*)&Wcat1, (void*)&Wcat2,
        (void*)&Wlinb, (void*)&Wo2ib,
        (void*)&b_ih1, (void*)&b_hh1, (void*)&b_ih2, (void*)&b_hh2,
        (void*)&b_lin, (void*)&b_o2i,
        (void*)&hh0, (void*)&hh1, (void*)&outp, (void*)&bar
    };
    hipLaunchCooperativeKernel((void*)lstm_persist, dim3(NBLK), dim3(512),
                               kargs, 0, stream);
}